// Round 2
// baseline (1218.816 us; speedup 1.0000x reference)
//
#include <hip/hip_runtime.h>
#include <hip/hip_bf16.h>

// NewellGRUModel: B=512, S=1024, F=16, H=64.
// One wave (64 threads) per batch item; lane j owns hidden unit j and gate
// columns (j, 64+j, 128+j). Recurrent + input-proj weights register-resident.
// h broadcast via LDS float4 reads (same-address = broadcast, conflict-free).
// x staged 16 steps/tile, double-buffered.
//
// Dtype-dual: a detect kernel writes mode (0=bf16, 1=fp32) to d_ws; both
// template instantiations launch and the non-matching one returns instantly.

template<bool BF16>
struct IO {
    static __device__ __forceinline__ float ld(const void* p, int i) {
        if constexpr (BF16) {
            unsigned short u = ((const unsigned short*)p)[i];
            union { unsigned int ui; float f; } c; c.ui = (unsigned int)u << 16;
            return c.f;
        } else {
            return ((const float*)p)[i];
        }
    }
    static __device__ __forceinline__ float4 ld4(const void* p, int i) {
        if constexpr (BF16) {
            uint2 raw = *(const uint2*)((const unsigned short*)p + i);
            union { unsigned int ui; float f; } c0, c1, c2, c3;
            c0.ui = raw.x << 16; c1.ui = raw.x & 0xffff0000u;
            c2.ui = raw.y << 16; c3.ui = raw.y & 0xffff0000u;
            return make_float4(c0.f, c1.f, c2.f, c3.f);
        } else {
            return *(const float4*)((const float*)p + i);
        }
    }
    static __device__ __forceinline__ void st(void* p, int i, float v) {
        if constexpr (BF16) ((__hip_bfloat16*)p)[i] = __float2bfloat16(v);
        else ((float*)p)[i] = v;
    }
};

// mode: 0 = buffers are bf16, 1 = buffers are fp32.
__global__ void detect_dtype_kernel(const void* rkbuf, int* flag) {
    const float* f = (const float*)rkbuf;
    int ok = 0;
    for (int i = 0; i < 64; ++i) {
        float a = fabsf(f[i]);
        ok += (a > 1e-5f && a < 2.0f) ? 1 : 0;
    }
    *flag = (ok >= 48) ? 1 : 0;
}

template<bool BF16>
__global__ __launch_bounds__(64, 1)
void gru_full_kernel(const void* __restrict__ inp, const void* __restrict__ gk,
                     const void* __restrict__ rk,  const void* __restrict__ gb,
                     const void* __restrict__ w1,  const void* __restrict__ b1v,
                     const void* __restrict__ gam, const void* __restrict__ bet,
                     const void* __restrict__ muv, const void* __restrict__ vav,
                     const void* __restrict__ w2,  const void* __restrict__ bb2,
                     const void* __restrict__ Tp,  const int* __restrict__ mode,
                     void* __restrict__ out)
{
    const int want = BF16 ? 0 : 1;
    if (*mode != want) return;   // uniform branch, whole block exits

    const int b = blockIdx.x;
    const int j = threadIdx.x;   // 0..63

    __shared__ __align__(16) float xs[2][16][16];  // [buf][step-in-tile][channel]
    __shared__ __align__(16) float hbuf[2][64];    // double-buffered hidden state

    using io = IO<BF16>;

    // ---- preload weights into registers (fully unrolled -> VGPRs) ----
    float wz[64], wr[64], wh[64];
#pragma unroll
    for (int k = 0; k < 64; ++k) {
        wz[k] = io::ld(rk, k*192 + j);
        wr[k] = io::ld(rk, k*192 + 64 + j);
        wh[k] = io::ld(rk, k*192 + 128 + j);
    }
    float kz[15], kr[15], kh[15];
#pragma unroll
    for (int k = 0; k < 15; ++k) {
        kz[k] = io::ld(gk, k*192 + j);
        kr[k] = io::ld(gk, k*192 + 64 + j);
        kh[k] = io::ld(gk, k*192 + 128 + j);
    }
    // gru_bias[0]=b_i (input proj), gru_bias[1]=b_r (recurrent)
    const float bz  = io::ld(gb, j)        + io::ld(gb, 192 + j);       // z gate
    const float br  = io::ld(gb, 64 + j)   + io::ld(gb, 192 + 64 + j);  // r gate
    const float bih = io::ld(gb, 128 + j);                              // xh bias
    const float brh = io::ld(gb, 192 + 128 + j);                        // rh bias

    hbuf[0][j] = 0.0f;   // h0 = 0

    const int xbase = b * 16384;             // b * 1024 * 16 elements
    // prefetch tile 0: 16 steps x 16 channels = 256 elems; lane loads 4
    float4 nxt = io::ld4(inp, xbase + j * 4);

    float h    = 0.0f;   // this lane's hidden unit
    float dsum = 0.0f;   // running sum of channel 15 (uniform across lanes)

    for (int t = 0; t < 64; ++t) {
        ((float4*)&xs[t & 1][0][0])[j] = nxt;
        if (t < 63) nxt = io::ld4(inp, xbase + (t + 1) * 256 + j * 4);
        __syncthreads();

        for (int s2 = 0; s2 < 16; ++s2) {
            const int s = t * 16 + s2;

            // broadcast-read x row (16 ch) from LDS
            const float4* xr4 = (const float4*)&xs[t & 1][s2][0];
            float xf[16];
            {
                float4 q;
                q = xr4[0]; xf[0]=q.x;  xf[1]=q.y;  xf[2]=q.z;  xf[3]=q.w;
                q = xr4[1]; xf[4]=q.x;  xf[5]=q.y;  xf[6]=q.z;  xf[7]=q.w;
                q = xr4[2]; xf[8]=q.x;  xf[9]=q.y;  xf[10]=q.z; xf[11]=q.w;
                q = xr4[3]; xf[12]=q.x; xf[13]=q.y; xf[14]=q.z; xf[15]=q.w;
            }

            float az = bz, ar = br, ax = bih, ah = brh;
#pragma unroll
            for (int k = 0; k < 15; ++k) {
                az = fmaf(xf[k], kz[k], az);
                ar = fmaf(xf[k], kr[k], ar);
                ax = fmaf(xf[k], kh[k], ax);
            }
            dsum += xf[15];   // channel 15 = delta_x_shifted

            const float4* hr4 = (const float4*)&hbuf[s & 1][0];
#pragma unroll
            for (int i = 0; i < 16; ++i) {
                float4 p = hr4[i];
                az = fmaf(p.x, wz[4*i+0], az);
                ar = fmaf(p.x, wr[4*i+0], ar);
                ah = fmaf(p.x, wh[4*i+0], ah);
                az = fmaf(p.y, wz[4*i+1], az);
                ar = fmaf(p.y, wr[4*i+1], ar);
                ah = fmaf(p.y, wh[4*i+1], ah);
                az = fmaf(p.z, wz[4*i+2], az);
                ar = fmaf(p.z, wr[4*i+2], ar);
                ah = fmaf(p.z, wh[4*i+2], ah);
                az = fmaf(p.w, wz[4*i+3], az);
                ar = fmaf(p.w, wr[4*i+3], ar);
                ah = fmaf(p.w, wh[4*i+3], ah);
            }

            const float z   = __builtin_amdgcn_rcpf(1.0f + __expf(-az));
            const float r   = __builtin_amdgcn_rcpf(1.0f + __expf(-ar));
            const float pre = fmaf(r, ah, ax);
            const float e2  = __expf(2.0f * pre);
            const float th  = 1.0f - 2.0f * __builtin_amdgcn_rcpf(e2 + 1.0f); // tanh
            h = fmaf(z, h - th, th);   // z*h + (1-z)*th

            hbuf[(s + 1) & 1][j] = h;
            __syncthreads();
        }
    }

    // ---- epilogue: delta effect + dense head, all in-wave ----
    const float T0 = io::ld(Tp, 0);
    const float st = h + T0 * dsum * (1.0f / 1024.0f);
    hbuf[0][j] = st;
    __syncthreads();

    float acc = io::ld(b1v, j);
#pragma unroll
    for (int k = 0; k < 64; ++k)
        acc = fmaf(hbuf[0][k], io::ld(w1, k*64 + j), acc);
    acc = fmaxf(acc, 0.0f);                                     // ReLU
    const float inv = rsqrtf(io::ld(vav, j) + 0.001f);          // BN_EPS
    acc = fmaf((acc - io::ld(muv, j)) * inv, io::ld(gam, j), io::ld(bet, j));

    float v = acc * io::ld(w2, j);
#pragma unroll
    for (int off = 32; off > 0; off >>= 1)
        v += __shfl_down(v, off);
    if (j == 0) io::st(out, b, v + io::ld(bb2, 0));
}

extern "C" void kernel_launch(void* const* d_in, const int* in_sizes, int n_in,
                              void* d_out, int out_size, void* d_ws, size_t ws_size,
                              hipStream_t stream)
{
    const void* inp = d_in[0];   // (512,1024,16)
    const void* gk  = d_in[1];   // (15,192)
    const void* rk  = d_in[2];   // (64,192)
    const void* gb  = d_in[3];   // (2,192)
    const void* w1  = d_in[4];   // (64,64)
    const void* b1v = d_in[5];   // (64,)
    const void* gam = d_in[6];
    const void* bet = d_in[7];
    const void* muv = d_in[8];
    const void* vav = d_in[9];
    const void* w2  = d_in[10];  // (64,1)
    const void* bb2 = d_in[11];  // (1,)
    const void* Tp  = d_in[12];  // (1,)

    int* flag = (int*)d_ws;
    detect_dtype_kernel<<<dim3(1), dim3(1), 0, stream>>>(rk, flag);
    gru_full_kernel<true ><<<dim3(512), dim3(64), 0, stream>>>(
        inp, gk, rk, gb, w1, b1v, gam, bet, muv, vav, w2, bb2, Tp, flag, d_out);
    gru_full_kernel<false><<<dim3(512), dim3(64), 0, stream>>>(
        inp, gk, rk, gb, w1, b1v, gam, bet, muv, vav, w2, bb2, Tp, flag, d_out);
}